// Round 7
// baseline (2430.995 us; speedup 1.0000x reference)
//
#include <hip/hip_runtime.h>
#include <hip/hip_bf16.h>
#include <math.h>

#define N_NODES 30000
#define N_EDGES 480000
#define N_GRAPH 64
#define DIN 24
#define HD 512
#define NL 6
#define NRG 235   // ceil(30000/128) row-groups

typedef __hip_bfloat16 bf16;
using short8 = __attribute__((ext_vector_type(8))) short;
using f32x4 = __attribute__((ext_vector_type(4))) float;

// async 16B/lane global->LDS: lds dest = lp + lane*16 (wave-uniform lp!)
#define ASYNC16(gp, lp)                                              \
    __builtin_amdgcn_global_load_lds(                                \
        (const __attribute__((address_space(1))) void*)(gp),         \
        (__attribute__((address_space(3))) void*)(lp), 16, 0, 0)

#define SCHED_FENCE() __builtin_amdgcn_sched_barrier(0)

__device__ __forceinline__ float sigmoidf_(float x) { return 1.0f / (1.0f + expf(-x)); }
__device__ __forceinline__ float b2f(unsigned short u) {
    return __uint_as_float(((unsigned int)u) << 16);
}
__device__ __forceinline__ unsigned short f2b(float f) {
    bf16 b = __float2bfloat16(f);
    return *(unsigned short*)&b;
}

// ---------------- encoder ---------------------------------------------------------
__global__ __launch_bounds__(256) void enc_kernel(const float* __restrict__ x,
                                                  const float* __restrict__ w,
                                                  const float* __restrict__ b,
                                                  bf16* __restrict__ h) {
    __shared__ float xs[DIN];
    int row = blockIdx.x;
    int tid = threadIdx.x;
    if (tid < DIN) xs[tid] = x[row * DIN + tid];
    __syncthreads();
    for (int c = tid; c < HD; c += 256) {
        float acc = b[c];
#pragma unroll
        for (int k = 0; k < DIN; k++) acc = fmaf(xs[k], w[k * HD + c], acc);
        h[(size_t)row * HD + c] = __float2bfloat16(acc);
    }
}

// ---------------- weight transpose + hi/lo split ----------------------------------
__global__ __launch_bounds__(256) void twcvt_kernel(const float* __restrict__ W,
                                                    bf16* __restrict__ WtH,
                                                    bf16* __restrict__ WtL, int Nc) {
    __shared__ float s[32][33];
    int l = blockIdx.z;
    const float* Wp = W + (size_t)l * HD * Nc;
    size_t ob = (size_t)l * HD * Nc;
    int k0 = blockIdx.y * 32, c0 = blockIdx.x * 32;
    int tx = threadIdx.x & 31, ty = threadIdx.x >> 5;
    for (int r = ty; r < 32; r += 8) s[r][tx] = Wp[(size_t)(k0 + r) * Nc + c0 + tx];
    __syncthreads();
    for (int r = ty; r < 32; r += 8) {
        float v = s[tx][r];
        unsigned short hu = f2b(v);
        float hf = b2f(hu);
        size_t o = ob + (size_t)(c0 + r) * HD + k0 + tx;
        *(unsigned short*)&WtH[o] = hu;
        WtL[o] = __float2bfloat16(v - hf);
    }
}

// ---------------- bf16 MFMA GEMM (hi/lo weights): tile 128x128 --------------------
// 4 waves col-split (wave owns 128r x 32c). Counted-vmcnt double-buffer pipeline:
// 6 loads/wave/tile; top-of-iter vmcnt(6) retires tile t only -- tile t+1's loads
// stay in flight across the barrier (never drain to 0 in steady state, T4).
// 48KB LDS -> 3 blocks/CU. XCD-banded grid (W L2-resident, A fetched once/XCD).
template <bool RELU>
__global__ __launch_bounds__(256, 3) void gemm_mfma(const bf16* __restrict__ A,
                                                    const bf16* __restrict__ WtH,
                                                    const bf16* __restrict__ WtL,
                                                    const float* __restrict__ bias,
                                                    bf16* __restrict__ C, int n) {
    // per buffer (bf16 elems): A [0,4096), BH [4096,8192), BL [8192,12288)
    __shared__ __align__(16) bf16 SB[2][12288];
    int id = blockIdx.x;
    int xcd = id & 7, kb = id >> 3;
    int bx = kb & 3;
    int by = (kb >> 2) * 8 + xcd;
    if (by >= (n + 127) / 128) return;
    int row0 = by * 128, col0 = bx * 128;

    int tid = threadIdx.x;
    int wv = tid >> 6, lane = tid & 63;
    int quad = lane >> 4, l16 = lane & 15;
    int crow = lane >> 2, cseg = lane & 3;
    int gseg = cseg ^ ((crow >> 1) & 3);          // 2-way-free swizzle
    int fsw = (quad ^ ((l16 >> 1) & 3)) * 8;
    f32x4 acc[2][8] = {};

    // 24 staging chunks (A:0-7, BH:8-15, BL:16-23), 6 per wave
    const bf16* gsrc[6];
    int glds[6];
#pragma unroll
    for (int j = 0; j < 6; j++) {
        int c = wv * 6 + j;
        if (c < 8) {
            int gr = row0 + c * 16 + crow;
            if (gr > n - 1) gr = n - 1;           // clamp; dead rows guarded at write
            gsrc[j] = A + (size_t)gr * HD + gseg * 8;
            glds[j] = c * 512;
        } else if (c < 16) {
            gsrc[j] = WtH + (size_t)(col0 + (c - 8) * 16 + crow) * HD + gseg * 8;
            glds[j] = 4096 + (c - 8) * 512;
        } else {
            gsrc[j] = WtL + (size_t)(col0 + (c - 16) * 16 + crow) * HD + gseg * 8;
            glds[j] = 8192 + (c - 16) * 512;
        }
    }
    auto stage = [&](int kt, int nb) {
#pragma unroll
        for (int j = 0; j < 6; j++) ASYNC16(gsrc[j] + kt, &SB[nb][glds[j]]);
    };

    stage(0, 0);
    stage(32, 1);
    for (int t16 = 0; t16 < 16; t16++) {
        int b = t16 & 1;
        if (t16 == 15) asm volatile("s_waitcnt vmcnt(0)" ::: "memory");
        else           asm volatile("s_waitcnt vmcnt(6)" ::: "memory");
        SCHED_FENCE();
        __builtin_amdgcn_s_barrier();             // tile t landed; buffer b valid
        SCHED_FENCE();
        short8 bfr[2][2];
#pragma unroll
        for (int t = 0; t < 2; t++) {
            int fo = ((wv * 2 + t) * 16 + l16) * 32 + fsw;
            bfr[t][0] = *(const short8*)&SB[b][4096 + fo];
            bfr[t][1] = *(const short8*)&SB[b][8192 + fo];
        }
        __builtin_amdgcn_s_setprio(1);
#pragma unroll
        for (int i = 0; i < 8; i++) {
            short8 af = *(const short8*)&SB[b][(i * 16 + l16) * 32 + fsw];
#pragma unroll
            for (int t = 0; t < 2; t++) {
                acc[t][i] = __builtin_amdgcn_mfma_f32_16x16x32_bf16(af, bfr[t][0], acc[t][i], 0, 0, 0);
                acc[t][i] = __builtin_amdgcn_mfma_f32_16x16x32_bf16(af, bfr[t][1], acc[t][i], 0, 0, 0);
            }
        }
        __builtin_amdgcn_s_setprio(0);
        asm volatile("s_waitcnt lgkmcnt(0)" ::: "memory");
        SCHED_FENCE();
        __builtin_amdgcn_s_barrier();             // all waves done reading buffer b
        SCHED_FENCE();
        if (t16 < 14) stage((t16 + 2) * 32, b);   // full-iter landing window
    }
    // ---- epilogue: stage bf16 tile in LDS, then coalesced 16B/lane writes ----
    bf16* Cs = (bf16*)SB;                         // 128 x 132 (pad) = 33.8 KB
#pragma unroll
    for (int t = 0; t < 2; t++) {
        int colL = (wv * 2 + t) * 16 + l16;
        float bb = bias[col0 + colL];
#pragma unroll
        for (int i = 0; i < 8; i++) {
#pragma unroll
            for (int r = 0; r < 4; r++) {
                int rowL = i * 16 + quad * 4 + r;
                float v = acc[t][i][r] + bb;
                if (RELU) v = fmaxf(v, 0.0f);
                Cs[rowL * 132 + colL] = __float2bfloat16(v);
            }
        }
    }
    __syncthreads();
    const unsigned short* cp = (const unsigned short*)Cs;
#pragma unroll
    for (int pass = 0; pass < 8; pass++) {
        int rowL = pass * 16 + (tid >> 4);
        int row = row0 + rowL;
        int cc = (tid & 15) * 8;
        if (row < n) {
            ushort4 a0 = *(const ushort4*)&cp[rowL * 132 + cc];
            ushort4 a1 = *(const ushort4*)&cp[rowL * 132 + cc + 4];
            uint4 ov;
            ov.x = ((unsigned int)a0.y << 16) | a0.x;
            ov.y = ((unsigned int)a0.w << 16) | a0.z;
            ov.z = ((unsigned int)a1.y << 16) | a1.x;
            ov.w = ((unsigned int)a1.w << 16) | a1.z;
            *(uint4*)&((unsigned short*)C)[(size_t)row * HD + col0 + cc] = ov;
        }
    }
}

// ---------------- fused GRU (MFMA, hi/lo, col-split, counted-vmcnt pipeline) ------
// tile 128r x 64c, 4 waves each own 128r x 16c. 80KB LDS, 2 blocks/CU.
// M/H double-buffered (4 chunks/wave), Ws single-buffered (12 chunks/wave).
// Per-wave FIFO: [... W(t):12][MH(t+1):4][W(t+1):12][MH(t+2):4 ...]; top-of-iter
// vmcnt(4) retires {MH(t), W(t)} while leaving later tiles' loads IN FLIGHT.
// Never vmcnt(0) in steady state (T4); vmcnt(0) only on the final iteration.
__global__ __launch_bounds__(256, 2) void gru_mfma(const bf16* __restrict__ M,
                                                   const bf16* __restrict__ Hc,
                                                   const bf16* __restrict__ WiH,
                                                   const bf16* __restrict__ WiL,
                                                   const bf16* __restrict__ WhH,
                                                   const bf16* __restrict__ WhL,
                                                   const float* __restrict__ bih,
                                                   const float* __restrict__ bhh,
                                                   bf16* __restrict__ Hn, int n) {
    __shared__ __align__(16) bf16 Ms[2][128 * 32];
    __shared__ __align__(16) bf16 Hs[2][128 * 32];
    __shared__ __align__(16) bf16 Ws[12 * 64 * 32];
    int id = blockIdx.x;
    int xcd = id & 7, kb = id >> 3;
    int band = xcd >> 1, colg = xcd & 1;
    int bx = colg * 4 + (kb & 3);
    int by = (kb >> 2) * 4 + band;
    if (by >= (n + 127) / 128) return;
    int row0 = by * 128, col0 = bx * 64;

    int tid = threadIdx.x;
    int wv = tid >> 6, lane = tid & 63;
    int quad = lane >> 4, l16 = lane & 15;
    int crow = lane >> 2, cseg = lane & 3;
    int gseg = cseg ^ ((crow >> 1) & 3);
    int fsw = (quad ^ ((l16 >> 1) & 3)) * 8;
    f32x4 aR[8] = {}, aZ[8] = {}, aI[8] = {}, aHn[8] = {};

    // M/H staging: 16 chunks (M:0-7, H:8-15), 4 per wave; wave w -> chunks 4w..4w+3
    const bf16* mhsrc[4];
    int mhrch[4];
    int mhmat[4];
#pragma unroll
    for (int j = 0; j < 4; j++) {
        int c = wv * 4 + j;
        int mat = c >> 3, rch = c & 7;
        int gr = row0 + rch * 16 + crow;
        if (gr > n - 1) gr = n - 1;
        mhsrc[j] = (mat ? Hc : M) + (size_t)gr * HD + gseg * 8;
        mhrch[j] = rch * 512;
        mhmat[j] = mat;
    }
    // weight staging: 12 panels, 3 per wave (4 chunks each = 12 chunks/wave)
    const bf16* wbase[4] = {WiH, WiL, WhH, WhL};
    const bf16* wgp[3];
    int wldsb[3];
#pragma unroll
    for (int pp = 0; pp < 3; pp++) {
        int p = wv * 3 + pp;                      // 0..11
        int mat = (p >= 6);
        int q = p - mat * 6;
        int g = q >> 1, pl = q & 1;
        const bf16* base = wbase[mat * 2 + pl] + (size_t)(g * HD + col0) * HD;
        wgp[pp] = base + crow * HD + gseg * 8;
        wldsb[pp] = p * 2048;
    }
    auto stageMH = [&](int kt, int nb) {
#pragma unroll
        for (int j = 0; j < 4; j++)
            ASYNC16(mhsrc[j] + kt, (mhmat[j] ? &Hs[nb][mhrch[j]] : &Ms[nb][mhrch[j]]));
    };
    auto stageW = [&](int kt) {
#pragma unroll
        for (int pp = 0; pp < 3; pp++)
#pragma unroll
            for (int s = 0; s < 4; s++)
                ASYNC16(wgp[pp] + (size_t)s * 16 * HD + kt, &Ws[wldsb[pp] + s * 512]);
    };

    // prologue FIFO: [MH(0):4][W(0):12][MH(1):4]
    stageMH(0, 0);
    stageW(0);
    stageMH(32, 1);
    int fo = (wv * 16 + l16) * 32 + fsw;
    for (int t16 = 0; t16 < 16; t16++) {
        int b = t16 & 1;
        int kt = t16 * 32;
        if (t16 == 15) asm volatile("s_waitcnt vmcnt(0)" ::: "memory");
        else           asm volatile("s_waitcnt vmcnt(4)" ::: "memory");
        SCHED_FENCE();
        __builtin_amdgcn_s_barrier();             // MH(t) [buf b] and W(t) landed
        SCHED_FENCE();
        short8 wrh = *(const short8*)&Ws[0 * 2048 + fo];
        short8 wrl = *(const short8*)&Ws[1 * 2048 + fo];
        short8 wzh = *(const short8*)&Ws[2 * 2048 + fo];
        short8 wzl = *(const short8*)&Ws[3 * 2048 + fo];
        short8 wnh = *(const short8*)&Ws[4 * 2048 + fo];
        short8 wnl = *(const short8*)&Ws[5 * 2048 + fo];
        short8 vrh = *(const short8*)&Ws[6 * 2048 + fo];
        short8 vrl = *(const short8*)&Ws[7 * 2048 + fo];
        short8 vzh = *(const short8*)&Ws[8 * 2048 + fo];
        short8 vzl = *(const short8*)&Ws[9 * 2048 + fo];
        short8 vnh = *(const short8*)&Ws[10 * 2048 + fo];
        short8 vnl = *(const short8*)&Ws[11 * 2048 + fo];
        asm volatile("s_waitcnt lgkmcnt(0)" ::: "memory");
        SCHED_FENCE();
        __builtin_amdgcn_s_barrier();             // all waves read Ws -> free
        SCHED_FENCE();
        if (t16 < 15) stageW(kt + 32);            // W(t+1): lands under MFMA below
        __builtin_amdgcn_s_setprio(1);
#pragma unroll
        for (int i = 0; i < 8; i++) {
            short8 am = *(const short8*)&Ms[b][(i * 16 + l16) * 32 + fsw];
            short8 ah = *(const short8*)&Hs[b][(i * 16 + l16) * 32 + fsw];
            aR[i] = __builtin_amdgcn_mfma_f32_16x16x32_bf16(am, wrh, aR[i], 0, 0, 0);
            aR[i] = __builtin_amdgcn_mfma_f32_16x16x32_bf16(am, wrl, aR[i], 0, 0, 0);
            aR[i] = __builtin_amdgcn_mfma_f32_16x16x32_bf16(ah, vrh, aR[i], 0, 0, 0);
            aR[i] = __builtin_amdgcn_mfma_f32_16x16x32_bf16(ah, vrl, aR[i], 0, 0, 0);
            aZ[i] = __builtin_amdgcn_mfma_f32_16x16x32_bf16(am, wzh, aZ[i], 0, 0, 0);
            aZ[i] = __builtin_amdgcn_mfma_f32_16x16x32_bf16(am, wzl, aZ[i], 0, 0, 0);
            aZ[i] = __builtin_amdgcn_mfma_f32_16x16x32_bf16(ah, vzh, aZ[i], 0, 0, 0);
            aZ[i] = __builtin_amdgcn_mfma_f32_16x16x32_bf16(ah, vzl, aZ[i], 0, 0, 0);
            aI[i] = __builtin_amdgcn_mfma_f32_16x16x32_bf16(am, wnh, aI[i], 0, 0, 0);
            aI[i] = __builtin_amdgcn_mfma_f32_16x16x32_bf16(am, wnl, aI[i], 0, 0, 0);
            aHn[i] = __builtin_amdgcn_mfma_f32_16x16x32_bf16(ah, vnh, aHn[i], 0, 0, 0);
            aHn[i] = __builtin_amdgcn_mfma_f32_16x16x32_bf16(ah, vnl, aHn[i], 0, 0, 0);
        }
        __builtin_amdgcn_s_setprio(0);
        asm volatile("s_waitcnt lgkmcnt(0)" ::: "memory");
        SCHED_FENCE();
        __builtin_amdgcn_s_barrier();             // all waves read MH[b] -> free
        SCHED_FENCE();
        if (t16 < 14) stageMH(kt + 64, b);        // MH(t+2): ~1.5-iter window
    }
    // ---- epilogue: gates -> stage z, (1-z)*n (f32, halves) -> coalesced RMW ----
    float* Zs32 = (float*)Ws;                     // [64][66] f32
    float* Ps32 = Zs32 + 64 * 66;                 // [64][66] f32 (33.8 KB total)
    int colL = wv * 16 + l16;
    int col = col0 + colL;
    float brz = bih[col] + bhh[col];
    float bzz = bih[HD + col] + bhh[HD + col];
    float bin_ = bih[2 * HD + col];
    float bhn_ = bhh[2 * HD + col];
    const unsigned short* hp = (const unsigned short*)Hc;
    unsigned short* op = (unsigned short*)Hn;
#pragma unroll
    for (int hhalf = 0; hhalf < 2; hhalf++) {
#pragma unroll
        for (int i = 0; i < 4; i++) {
            int ii = hhalf * 4 + i;
#pragma unroll
            for (int r = 0; r < 4; r++) {
                int rowL = i * 16 + quad * 4 + r;  // 0..63 within half
                float rg = sigmoidf_(aR[ii][r] + brz);
                float zg = sigmoidf_(aZ[ii][r] + bzz);
                float ng = tanhf(aI[ii][r] + bin_ + rg * (aHn[ii][r] + bhn_));
                Zs32[rowL * 66 + colL] = zg;
                Ps32[rowL * 66 + colL] = (1.0f - zg) * ng;
            }
        }
        __syncthreads();
#pragma unroll
        for (int sub = 0; sub < 2; sub++) {
            int rowL = sub * 32 + (tid >> 3);
            int row = row0 + hhalf * 64 + rowL;
            int cc = (tid & 7) * 8;
            if (row < n) {
                uint4 hv = *(const uint4*)&hp[(size_t)row * HD + col0 + cc];
                unsigned int hw[4] = {hv.x, hv.y, hv.z, hv.w};
                unsigned int ow[4];
#pragma unroll
                for (int q = 0; q < 4; q++) {
                    float h0 = b2f((unsigned short)(hw[q] & 0xffffu));
                    float h1 = b2f((unsigned short)(hw[q] >> 16));
                    float z0 = Zs32[rowL * 66 + cc + 2 * q];
                    float z1 = Zs32[rowL * 66 + cc + 2 * q + 1];
                    float p0 = Ps32[rowL * 66 + cc + 2 * q];
                    float p1 = Ps32[rowL * 66 + cc + 2 * q + 1];
                    float o0 = fmaf(z0, h0, p0);
                    float o1 = fmaf(z1, h1, p1);
                    ow[q] = ((unsigned int)f2b(o1) << 16) | f2b(o0);
                }
                uint4 ov = {ow[0], ow[1], ow[2], ow[3]};
                *(uint4*)&op[(size_t)row * HD + col0 + cc] = ov;
            }
        }
        __syncthreads();
    }
}

// ---------------- CSR build -------------------------------------------------------
__global__ __launch_bounds__(256) void deg_kernel(const int* __restrict__ dst,
                                                  int* __restrict__ deg) {
    int e = blockIdx.x * 256 + threadIdx.x;
    if (e < N_EDGES) atomicAdd(&deg[dst[e]], 1);
}

__global__ __launch_bounds__(1024) void scan_kernel(const int* __restrict__ deg,
                                                    int* __restrict__ offs) {
    __shared__ int buf[1024];
    __shared__ int carry_s;
    int tid = threadIdx.x;
    if (tid == 0) carry_s = 0;
    __syncthreads();
    for (int base = 0; base < N_NODES; base += 1024) {
        int v = (base + tid < N_NODES) ? deg[base + tid] : 0;
        buf[tid] = v;
        __syncthreads();
        for (int s = 1; s < 1024; s <<= 1) {
            int t = (tid >= s) ? buf[tid - s] : 0;
            __syncthreads();
            buf[tid] += t;
            __syncthreads();
        }
        int incl = buf[tid];
        if (base + tid < N_NODES) offs[base + tid] = carry_s + incl - v;
        __syncthreads();
        if (tid == 0) carry_s += buf[1023];
        __syncthreads();
    }
    if (tid == 0) offs[N_NODES] = carry_s;
}

__global__ __launch_bounds__(256) void bucket_kernel(const int* __restrict__ src,
                                                     const int* __restrict__ dst,
                                                     const int* __restrict__ offs,
                                                     int* __restrict__ cursor,
                                                     unsigned short* __restrict__ elist) {
    int e = blockIdx.x * 256 + threadIdx.x;
    if (e >= N_EDGES) return;
    int d = dst[e];
    int pos = atomicAdd(&cursor[d], 1);
    elist[offs[d] + pos] = (unsigned short)src[e];
}

// ---------------- gather-sum ------------------------------------------------------
__global__ __launch_bounds__(256) void gather_kernel(const bf16* __restrict__ msg,
                                                     bf16* __restrict__ m,
                                                     const unsigned short* __restrict__ elist,
                                                     const int* __restrict__ offs) {
    int nid = blockIdx.x, tid = threadIdx.x;
    int beg = offs[nid], end = offs[nid + 1];
    const unsigned int* mp = (const unsigned int*)msg;
    unsigned int u = mp[(size_t)nid * 256 + tid];
    float ax = b2f((unsigned short)(u & 0xffffu));
    float ay = b2f((unsigned short)(u >> 16));
    int e = beg;
    for (; e + 3 < end; e += 4) {
        unsigned int v0 = mp[(size_t)elist[e] * 256 + tid];
        unsigned int v1 = mp[(size_t)elist[e + 1] * 256 + tid];
        unsigned int v2 = mp[(size_t)elist[e + 2] * 256 + tid];
        unsigned int v3 = mp[(size_t)elist[e + 3] * 256 + tid];
        ax += b2f((unsigned short)(v0 & 0xffffu)) + b2f((unsigned short)(v1 & 0xffffu)) +
              b2f((unsigned short)(v2 & 0xffffu)) + b2f((unsigned short)(v3 & 0xffffu));
        ay += b2f((unsigned short)(v0 >> 16)) + b2f((unsigned short)(v1 >> 16)) +
              b2f((unsigned short)(v2 >> 16)) + b2f((unsigned short)(v3 >> 16));
    }
    for (; e < end; e++) {
        unsigned int v0 = mp[(size_t)elist[e] * 256 + tid];
        ax += b2f((unsigned short)(v0 & 0xffffu));
        ay += b2f((unsigned short)(v0 >> 16));
    }
    unsigned int out = ((unsigned int)f2b(ay) << 16) | (unsigned int)f2b(ax);
    ((unsigned int*)m)[(size_t)nid * 256 + tid] = out;
}

// ---------------- pooling (segmented, batch sorted -> no atomics) -----------------
__global__ __launch_bounds__(256) void pool_kernel(const bf16* __restrict__ h,
                                                   const int* __restrict__ batch,
                                                   float* __restrict__ pooled,
                                                   float* __restrict__ cnt) {
    int g = blockIdx.x;
    int col = blockIdx.y * 256 + threadIdx.x;
    // lower_bound for g and g+1 in sorted batch
    int lo = 0, hi = N_NODES;
    while (lo < hi) { int mid = (lo + hi) >> 1; if (batch[mid] < g) lo = mid + 1; else hi = mid; }
    int gs = lo;
    hi = N_NODES;
    while (lo < hi) { int mid = (lo + hi) >> 1; if (batch[mid] < g + 1) lo = mid + 1; else hi = mid; }
    int ge = lo;
    const unsigned short* hp = (const unsigned short*)h;
    float acc = 0.0f;
    int r = gs;
    for (; r + 3 < ge; r += 4) {
        acc += b2f(hp[(size_t)r * HD + col]) + b2f(hp[(size_t)(r + 1) * HD + col]) +
               b2f(hp[(size_t)(r + 2) * HD + col]) + b2f(hp[(size_t)(r + 3) * HD + col]);
    }
    for (; r < ge; r++) acc += b2f(hp[(size_t)r * HD + col]);
    pooled[g * HD + col] = acc;
    if (blockIdx.y == 0 && threadIdx.x == 0) cnt[g] = (float)(ge - gs);
}

__global__ __launch_bounds__(256) void head_kernel(const float* __restrict__ pooled,
                                                   const float* __restrict__ cnt,
                                                   const float* __restrict__ w1,
                                                   const float* __restrict__ b1,
                                                   const float* __restrict__ w2,
                                                   const float* __restrict__ b2,
                                                   float* __restrict__ out) {
    __shared__ float prow[HD];
    __shared__ float red[256];
    int g = blockIdx.x, tid = threadIdx.x;
    float c = fmaxf(cnt[g], 1.0f);
    for (int j = tid; j < HD; j += 256) prow[j] = pooled[g * HD + j] / c;
    __syncthreads();
    float acc = b1[tid];
    for (int k = 0; k < HD; k++) acc = fmaf(prow[k], w1[k * 256 + tid], acc);
    red[tid] = fmaxf(acc, 0.0f) * w2[tid];
    __syncthreads();
    for (int s = 128; s > 0; s >>= 1) {
        if (tid < s) red[tid] += red[tid + s];
        __syncthreads();
    }
    if (tid == 0) out[g] = red[0] + b2[0];
}

// ---------------- launch ----------------------------------------------------------
extern "C" void kernel_launch(void* const* d_in, const int* in_sizes, int n_in,
                              void* d_out, int out_size, void* d_ws, size_t ws_size,
                              hipStream_t stream) {
    const float* x = (const float*)d_in[0];
    const int* eidx = (const int*)d_in[1];
    const int* batch = (const int*)d_in[2];
    const float* enc_w = (const float*)d_in[3];
    const float* enc_b = (const float*)d_in[4];
    const float* mlp_w1 = (const float*)d_in[5];
    const float* mlp_b1 = (const float*)d_in[6];
    const float* mlp_w2 = (const float*)d_in[7];
    const float* mlp_b2 = (const float*)d_in[8];
    const float* gru_wih = (const float*)d_in[9];
    const float* gru_whh = (const float*)d_in[10];
    const float* gru_bih = (const float*)d_in[11];
    const float* gru_bhh = (const float*)d_in[12];
    const float* head_w1 = (const float*)d_in[13];
    const float* head_b1 = (const float*)d_in[14];
    const float* head_w2 = (const float*)d_in[15];
    const float* head_b2 = (const float*)d_in[16];
    const int* src = eidx;
    const int* dst = eidx + N_EDGES;

    const size_t NH = (size_t)N_NODES * HD;
    char* p = (char*)d_ws;
    auto alloc = [&](size_t bytes) { char* q = p; p += (bytes + 255) & ~(size_t)255; return q; };
    bf16* S0 = (bf16*)alloc(NH * 2);
    bf16* S1 = (bf16*)alloc(NH * 2);
    bf16* S2 = (bf16*)alloc(NH * 2);
    bf16* w1tH = (bf16*)alloc((size_t)NL * HD * HD * 2);
    bf16* w1tL = (bf16*)alloc((size_t)NL * HD * HD * 2);
    bf16* w2tH = (bf16*)alloc((size_t)NL * HD * HD * 2);
    bf16* w2tL = (bf16*)alloc((size_t)NL * HD * HD * 2);
    bf16* wihtH = (bf16*)alloc((size_t)NL * 3 * HD * HD * 2);
    bf16* wihtL = (bf16*)alloc((size_t)NL * 3 * HD * HD * 2);
    bf16* whhtH = (bf16*)alloc((size_t)NL * 3 * HD * HD * 2);
    bf16* whhtL = (bf16*)alloc((size_t)NL * 3 * HD * HD * 2);
    float* pooled = (float*)alloc((size_t)N_GRAPH * HD * 4);
    float* cnt = (float*)alloc(N_GRAPH * 4);
    int* deg = (int*)alloc((N_NODES + 1) * 4);  // also cursor
    int* offs = (int*)alloc((N_NODES + 1) * 4);
    unsigned short* elist = (unsigned short*)alloc((size_t)N_EDGES * 2);
    // total ~144 MB (proven-safe envelope)

    twcvt_kernel<<<dim3(16, 16, NL), 256, 0, stream>>>(mlp_w1, w1tH, w1tL, HD);
    twcvt_kernel<<<dim3(16, 16, NL), 256, 0, stream>>>(mlp_w2, w2tH, w2tL, HD);
    twcvt_kernel<<<dim3(48, 16, NL), 256, 0, stream>>>(gru_wih, wihtH, wihtL, 3 * HD);
    twcvt_kernel<<<dim3(48, 16, NL), 256, 0, stream>>>(gru_whh, whhtH, whhtL, 3 * HD);

    hipMemsetAsync(deg, 0, (N_NODES + 1) * sizeof(int), stream);
    deg_kernel<<<(N_EDGES + 255) / 256, 256, 0, stream>>>(dst, deg);
    scan_kernel<<<1, 1024, 0, stream>>>(deg, offs);
    hipMemsetAsync(deg, 0, (N_NODES + 1) * sizeof(int), stream);
    bucket_kernel<<<(N_EDGES + 255) / 256, 256, 0, stream>>>(src, dst, offs, deg, elist);

    enc_kernel<<<N_NODES, 256, 0, stream>>>(x, enc_w, enc_b, S0);

    bf16* hcur = S0;
    bf16* hoth = S1;
    // XCD-banded 1-D grids (proven FETCH win in R5)
    int ggrid = 8 * ((NRG + 7) / 8) * 4;    // 960
    int ugrid = 8 * ((NRG + 3) / 4) * 4;    // 1888

    for (int l = 0; l < NL; l++) {
        size_t wsq = (size_t)l * HD * HD;
        size_t wgq = (size_t)l * 3 * HD * HD;
        const float* b1 = mlp_b1 + (size_t)l * HD;
        const float* b2 = mlp_b2 + (size_t)l * HD;
        const float* bih = gru_bih + (size_t)l * 3 * HD;
        const float* bhh = gru_bhh + (size_t)l * 3 * HD;

        gemm_mfma<true><<<ggrid, 256, 0, stream>>>(hcur, w1tH + wsq, w1tL + wsq, b1, hoth, N_NODES);
        gemm_mfma<false><<<ggrid, 256, 0, stream>>>(hoth, w2tH + wsq, w2tL + wsq, b2, S2, N_NODES);
        gather_kernel<<<N_NODES, 256, 0, stream>>>(S2, hoth, elist, offs);
        gru_mfma<<<ugrid, 256, 0, stream>>>(hoth, hcur, wihtH + wgq, wihtL + wgq,
                                            whhtH + wgq, whhtL + wgq, bih, bhh, S2, N_NODES);
        bf16* newh = S2;
        S2 = hcur;
        hcur = newh;
    }

    pool_kernel<<<dim3(N_GRAPH, 2), 256, 0, stream>>>(hcur, batch, pooled, cnt);
    head_kernel<<<N_GRAPH, 256, 0, stream>>>(pooled, cnt, head_w1, head_b1, head_w2, head_b2,
                                             (float*)d_out);
}

// Round 8
// 2425.833 us; speedup vs baseline: 1.0021x; 1.0021x over previous
//
#include <hip/hip_runtime.h>
#include <hip/hip_bf16.h>
#include <math.h>

#define N_NODES 30000
#define N_EDGES 480000
#define N_GRAPH 64
#define DIN 24
#define HD 512
#define NL 6
#define NRG 235   // ceil(30000/128) row-groups

typedef __hip_bfloat16 bf16;
using short8 = __attribute__((ext_vector_type(8))) short;
using f32x4 = __attribute__((ext_vector_type(4))) float;

// async 16B/lane global->LDS: lds dest = lp + lane*16 (wave-uniform lp!)
#define ASYNC16(gp, lp)                                              \
    __builtin_amdgcn_global_load_lds(                                \
        (const __attribute__((address_space(1))) void*)(gp),         \
        (__attribute__((address_space(3))) void*)(lp), 16, 0, 0)

#define SCHED_FENCE() __builtin_amdgcn_sched_barrier(0)
// phase barrier: pin instruction placement on both sides
#define BARX()                                                       \
    do {                                                             \
        SCHED_FENCE();                                               \
        __builtin_amdgcn_s_barrier();                                \
        SCHED_FENCE();                                               \
    } while (0)
// per-wave LDS-read drain (stagger point; rule-18 fence after)
#define LGKM0()                                                      \
    do {                                                             \
        asm volatile("s_waitcnt lgkmcnt(0)" ::: "memory");           \
        SCHED_FENCE();                                               \
    } while (0)

__device__ __forceinline__ float sigmoidf_(float x) { return 1.0f / (1.0f + expf(-x)); }
__device__ __forceinline__ float b2f(unsigned short u) {
    return __uint_as_float(((unsigned int)u) << 16);
}
__device__ __forceinline__ unsigned short f2b(float f) {
    bf16 b = __float2bfloat16(f);
    return *(unsigned short*)&b;
}

// ---------------- encoder ---------------------------------------------------------
__global__ __launch_bounds__(256) void enc_kernel(const float* __restrict__ x,
                                                  const float* __restrict__ w,
                                                  const float* __restrict__ b,
                                                  bf16* __restrict__ h) {
    __shared__ float xs[DIN];
    int row = blockIdx.x;
    int tid = threadIdx.x;
    if (tid < DIN) xs[tid] = x[row * DIN + tid];
    __syncthreads();
    for (int c = tid; c < HD; c += 256) {
        float acc = b[c];
#pragma unroll
        for (int k = 0; k < DIN; k++) acc = fmaf(xs[k], w[k * HD + c], acc);
        h[(size_t)row * HD + c] = __float2bfloat16(acc);
    }
}

// ---------------- weight transpose + hi/lo split ----------------------------------
__global__ __launch_bounds__(256) void twcvt_kernel(const float* __restrict__ W,
                                                    bf16* __restrict__ WtH,
                                                    bf16* __restrict__ WtL, int Nc) {
    __shared__ float s[32][33];
    int l = blockIdx.z;
    const float* Wp = W + (size_t)l * HD * Nc;
    size_t ob = (size_t)l * HD * Nc;
    int k0 = blockIdx.y * 32, c0 = blockIdx.x * 32;
    int tx = threadIdx.x & 31, ty = threadIdx.x >> 5;
    for (int r = ty; r < 32; r += 8) s[r][tx] = Wp[(size_t)(k0 + r) * Nc + c0 + tx];
    __syncthreads();
    for (int r = ty; r < 32; r += 8) {
        float v = s[tx][r];
        unsigned short hu = f2b(v);
        float hf = b2f(hu);
        size_t o = ob + (size_t)(c0 + r) * HD + k0 + tx;
        *(unsigned short*)&WtH[o] = hu;
        WtL[o] = __float2bfloat16(v - hf);
    }
}

// ---------------- bf16 MFMA GEMM (hi/lo weights): tile 128x128 --------------------
// 4 waves col-split. Counted-vmcnt double-buffer + 3-PHASE interleave per k-step:
// small read batches per phase + per-wave lgkm0 stagger -> LDS drain hides under
// MFMA (m201/T3 discipline). 48KB LDS -> 3 blocks/CU. XCD-banded grid.
template <bool RELU>
__global__ __launch_bounds__(256, 3) void gemm_mfma(const bf16* __restrict__ A,
                                                    const bf16* __restrict__ WtH,
                                                    const bf16* __restrict__ WtL,
                                                    const float* __restrict__ bias,
                                                    bf16* __restrict__ C, int n) {
    // per buffer (bf16 elems): A [0,4096), BH [4096,8192), BL [8192,12288)
    __shared__ __align__(16) bf16 SB[2][12288];
    int id = blockIdx.x;
    int xcd = id & 7, kb = id >> 3;
    int bx = kb & 3;
    int by = (kb >> 2) * 8 + xcd;
    if (by >= (n + 127) / 128) return;
    int row0 = by * 128, col0 = bx * 128;

    int tid = threadIdx.x;
    int wv = tid >> 6, lane = tid & 63;
    int quad = lane >> 4, l16 = lane & 15;
    int crow = lane >> 2, cseg = lane & 3;
    int gseg = cseg ^ ((crow >> 1) & 3);          // 2-way-free swizzle
    int fsw = (quad ^ ((l16 >> 1) & 3)) * 8;
    f32x4 acc[2][8] = {};

    // 24 staging chunks (A:0-7, BH:8-15, BL:16-23), 6 per wave
    const bf16* gsrc[6];
    int glds[6];
#pragma unroll
    for (int j = 0; j < 6; j++) {
        int c = wv * 6 + j;
        if (c < 8) {
            int gr = row0 + c * 16 + crow;
            if (gr > n - 1) gr = n - 1;           // clamp; dead rows guarded at write
            gsrc[j] = A + (size_t)gr * HD + gseg * 8;
            glds[j] = c * 512;
        } else if (c < 16) {
            gsrc[j] = WtH + (size_t)(col0 + (c - 8) * 16 + crow) * HD + gseg * 8;
            glds[j] = 4096 + (c - 8) * 512;
        } else {
            gsrc[j] = WtL + (size_t)(col0 + (c - 16) * 16 + crow) * HD + gseg * 8;
            glds[j] = 8192 + (c - 16) * 512;
        }
    }
    auto stage = [&](int kt, int nb) {
#pragma unroll
        for (int j = 0; j < 6; j++) ASYNC16(gsrc[j] + kt, &SB[nb][glds[j]]);
    };

    stage(0, 0);
    stage(32, 1);
    for (int t16 = 0; t16 < 16; t16++) {
        int b = t16 & 1;
        if (t16 == 15) asm volatile("s_waitcnt vmcnt(0)" ::: "memory");
        else           asm volatile("s_waitcnt vmcnt(6)" ::: "memory");
        BARX();                                   // tile t landed; buffer b valid
        short8 bh0, bl0, bh1, bl1;
        {
            int fo0 = ((wv * 2 + 0) * 16 + l16) * 32 + fsw;
            int fo1 = ((wv * 2 + 1) * 16 + l16) * 32 + fsw;
            bh0 = *(const short8*)&SB[b][4096 + fo0];
            bl0 = *(const short8*)&SB[b][8192 + fo0];
            bh1 = *(const short8*)&SB[b][4096 + fo1];
            bl1 = *(const short8*)&SB[b][8192 + fo1];
        }
        auto grp = [&](int i, short8 af) {
            acc[0][i] = __builtin_amdgcn_mfma_f32_16x16x32_bf16(af, bh0, acc[0][i], 0, 0, 0);
            acc[0][i] = __builtin_amdgcn_mfma_f32_16x16x32_bf16(af, bl0, acc[0][i], 0, 0, 0);
            acc[1][i] = __builtin_amdgcn_mfma_f32_16x16x32_bf16(af, bh1, acc[1][i], 0, 0, 0);
            acc[1][i] = __builtin_amdgcn_mfma_f32_16x16x32_bf16(af, bl1, acc[1][i], 0, 0, 0);
        };
        // ---- P0: B frags + rows 0-1 ----
        short8 af0 = *(const short8*)&SB[b][(0 * 16 + l16) * 32 + fsw];
        short8 af1 = *(const short8*)&SB[b][(1 * 16 + l16) * 32 + fsw];
        BARX();
        LGKM0();
        __builtin_amdgcn_s_setprio(1);
        grp(0, af0); grp(1, af1);
        __builtin_amdgcn_s_setprio(0);
        BARX();
        // ---- P1: rows 2-4 ----
        short8 af2 = *(const short8*)&SB[b][(2 * 16 + l16) * 32 + fsw];
        short8 af3 = *(const short8*)&SB[b][(3 * 16 + l16) * 32 + fsw];
        short8 af4 = *(const short8*)&SB[b][(4 * 16 + l16) * 32 + fsw];
        BARX();
        LGKM0();
        __builtin_amdgcn_s_setprio(1);
        grp(2, af2); grp(3, af3); grp(4, af4);
        __builtin_amdgcn_s_setprio(0);
        BARX();
        // ---- P2: rows 5-7 ----
        short8 af5 = *(const short8*)&SB[b][(5 * 16 + l16) * 32 + fsw];
        short8 af6 = *(const short8*)&SB[b][(6 * 16 + l16) * 32 + fsw];
        short8 af7 = *(const short8*)&SB[b][(7 * 16 + l16) * 32 + fsw];
        BARX();
        LGKM0();
        __builtin_amdgcn_s_setprio(1);
        grp(5, af5); grp(6, af6); grp(7, af7);
        __builtin_amdgcn_s_setprio(0);
        BARX();                                   // all reads of buffer b retired
        if (t16 < 14) stage((t16 + 2) * 32, b);   // full-iter landing window
    }
    // ---- epilogue: stage bf16 tile in LDS, then coalesced 16B/lane writes ----
    bf16* Cs = (bf16*)SB;                         // 128 x 132 (pad) = 33.8 KB
#pragma unroll
    for (int t = 0; t < 2; t++) {
        int colL = (wv * 2 + t) * 16 + l16;
        float bb = bias[col0 + colL];
#pragma unroll
        for (int i = 0; i < 8; i++) {
#pragma unroll
            for (int r = 0; r < 4; r++) {
                int rowL = i * 16 + quad * 4 + r;
                float v = acc[t][i][r] + bb;
                if (RELU) v = fmaxf(v, 0.0f);
                Cs[rowL * 132 + colL] = __float2bfloat16(v);
            }
        }
    }
    __syncthreads();
    const unsigned short* cp = (const unsigned short*)Cs;
#pragma unroll
    for (int pass = 0; pass < 8; pass++) {
        int rowL = pass * 16 + (tid >> 4);
        int row = row0 + rowL;
        int cc = (tid & 15) * 8;
        if (row < n) {
            ushort4 a0 = *(const ushort4*)&cp[rowL * 132 + cc];
            ushort4 a1 = *(const ushort4*)&cp[rowL * 132 + cc + 4];
            uint4 ov;
            ov.x = ((unsigned int)a0.y << 16) | a0.x;
            ov.y = ((unsigned int)a0.w << 16) | a0.z;
            ov.z = ((unsigned int)a1.y << 16) | a1.x;
            ov.w = ((unsigned int)a1.w << 16) | a1.z;
            *(uint4*)&((unsigned short*)C)[(size_t)row * HD + col0 + cc] = ov;
        }
    }
}

// ---------------- fused GRU (MFMA, hi/lo, col-split, 3-phase interleave) ----------
// tile 128r x 64c, 4 waves each own 128r x 16c. 80KB LDS, 2 blocks/CU.
// M/H double-buffered, Ws single-buffered; counted vmcnt(4) FIFO (R6). NEW: k-step
// split into 3 phases {reads, bar, lgkm0, MFMA, bar} -> per-wave stagger overlaps
// LDS drain with MFMA (read bursts 28 -> 14/6/8 per wave).
__global__ __launch_bounds__(256, 2) void gru_mfma(const bf16* __restrict__ M,
                                                   const bf16* __restrict__ Hc,
                                                   const bf16* __restrict__ WiH,
                                                   const bf16* __restrict__ WiL,
                                                   const bf16* __restrict__ WhH,
                                                   const bf16* __restrict__ WhL,
                                                   const float* __restrict__ bih,
                                                   const float* __restrict__ bhh,
                                                   bf16* __restrict__ Hn, int n) {
    __shared__ __align__(16) bf16 Ms[2][128 * 32];
    __shared__ __align__(16) bf16 Hs[2][128 * 32];
    __shared__ __align__(16) bf16 Ws[12 * 64 * 32];
    int id = blockIdx.x;
    int xcd = id & 7, kb = id >> 3;
    int band = xcd >> 1, colg = xcd & 1;
    int bx = colg * 4 + (kb & 3);
    int by = (kb >> 2) * 4 + band;
    if (by >= (n + 127) / 128) return;
    int row0 = by * 128, col0 = bx * 64;

    int tid = threadIdx.x;
    int wv = tid >> 6, lane = tid & 63;
    int quad = lane >> 4, l16 = lane & 15;
    int crow = lane >> 2, cseg = lane & 3;
    int gseg = cseg ^ ((crow >> 1) & 3);
    int fsw = (quad ^ ((l16 >> 1) & 3)) * 8;
    f32x4 aR[8] = {}, aZ[8] = {}, aI[8] = {}, aHn[8] = {};

    // M/H staging: 16 chunks (M:0-7, H:8-15), 4 per wave
    const bf16* mhsrc[4];
    int mhrch[4];
    int mhmat[4];
#pragma unroll
    for (int j = 0; j < 4; j++) {
        int c = wv * 4 + j;
        int mat = c >> 3, rch = c & 7;
        int gr = row0 + rch * 16 + crow;
        if (gr > n - 1) gr = n - 1;
        mhsrc[j] = (mat ? Hc : M) + (size_t)gr * HD + gseg * 8;
        mhrch[j] = rch * 512;
        mhmat[j] = mat;
    }
    // weight staging: 12 panels, 3 per wave
    const bf16* wbase[4] = {WiH, WiL, WhH, WhL};
    const bf16* wgp[3];
    int wldsb[3];
#pragma unroll
    for (int pp = 0; pp < 3; pp++) {
        int p = wv * 3 + pp;                      // 0..11
        int mat = (p >= 6);
        int q = p - mat * 6;
        int g = q >> 1, pl = q & 1;
        const bf16* base = wbase[mat * 2 + pl] + (size_t)(g * HD + col0) * HD;
        wgp[pp] = base + crow * HD + gseg * 8;
        wldsb[pp] = p * 2048;
    }
    auto stageMH = [&](int kt, int nb) {
#pragma unroll
        for (int j = 0; j < 4; j++)
            ASYNC16(mhsrc[j] + kt, (mhmat[j] ? &Hs[nb][mhrch[j]] : &Ms[nb][mhrch[j]]));
    };
    auto stageW = [&](int kt) {
#pragma unroll
        for (int pp = 0; pp < 3; pp++)
#pragma unroll
            for (int s = 0; s < 4; s++)
                ASYNC16(wgp[pp] + (size_t)s * 16 * HD + kt, &Ws[wldsb[pp] + s * 512]);
    };

    // prologue FIFO: [MH(0):4][W(0):12][MH(1):4]
    stageMH(0, 0);
    stageW(0);
    stageMH(32, 1);
    int fo = (wv * 16 + l16) * 32 + fsw;
    for (int t16 = 0; t16 < 16; t16++) {
        int b = t16 & 1;
        int kt = t16 * 32;
        if (t16 == 15) asm volatile("s_waitcnt vmcnt(0)" ::: "memory");
        else           asm volatile("s_waitcnt vmcnt(4)" ::: "memory");
        BARX();                                   // MH(t) [buf b] and W(t) landed
        // ---- P0: 12 W frags + row-group 0 ----
        short8 wrh = *(const short8*)&Ws[0 * 2048 + fo];
        short8 wrl = *(const short8*)&Ws[1 * 2048 + fo];
        short8 wzh = *(const short8*)&Ws[2 * 2048 + fo];
        short8 wzl = *(const short8*)&Ws[3 * 2048 + fo];
        short8 wnh = *(const short8*)&Ws[4 * 2048 + fo];
        short8 wnl = *(const short8*)&Ws[5 * 2048 + fo];
        short8 vrh = *(const short8*)&Ws[6 * 2048 + fo];
        short8 vrl = *(const short8*)&Ws[7 * 2048 + fo];
        short8 vzh = *(const short8*)&Ws[8 * 2048 + fo];
        short8 vzl = *(const short8*)&Ws[9 * 2048 + fo];
        short8 vnh = *(const short8*)&Ws[10 * 2048 + fo];
        short8 vnl = *(const short8*)&Ws[11 * 2048 + fo];
        auto grp = [&](int i, short8 am, short8 ah) {
            aR[i] = __builtin_amdgcn_mfma_f32_16x16x32_bf16(am, wrh, aR[i], 0, 0, 0);
            aR[i] = __builtin_amdgcn_mfma_f32_16x16x32_bf16(am, wrl, aR[i], 0, 0, 0);
            aR[i] = __builtin_amdgcn_mfma_f32_16x16x32_bf16(ah, vrh, aR[i], 0, 0, 0);
            aR[i] = __builtin_amdgcn_mfma_f32_16x16x32_bf16(ah, vrl, aR[i], 0, 0, 0);
            aZ[i] = __builtin_amdgcn_mfma_f32_16x16x32_bf16(am, wzh, aZ[i], 0, 0, 0);
            aZ[i] = __builtin_amdgcn_mfma_f32_16x16x32_bf16(am, wzl, aZ[i], 0, 0, 0);
            aZ[i] = __builtin_amdgcn_mfma_f32_16x16x32_bf16(ah, vzh, aZ[i], 0, 0, 0);
            aZ[i] = __builtin_amdgcn_mfma_f32_16x16x32_bf16(ah, vzl, aZ[i], 0, 0, 0);
            aI[i] = __builtin_amdgcn_mfma_f32_16x16x32_bf16(am, wnh, aI[i], 0, 0, 0);
            aI[i] = __builtin_amdgcn_mfma_f32_16x16x32_bf16(am, wnl, aI[i], 0, 0, 0);
            aHn[i] = __builtin_amdgcn_mfma_f32_16x16x32_bf16(ah, vnh, aHn[i], 0, 0, 0);
            aHn[i] = __builtin_amdgcn_mfma_f32_16x16x32_bf16(ah, vnl, aHn[i], 0, 0, 0);
        };
        short8 am0 = *(const short8*)&Ms[b][(0 * 16 + l16) * 32 + fsw];
        short8 ah0 = *(const short8*)&Hs[b][(0 * 16 + l16) * 32 + fsw];
        BARX();
        LGKM0();
        __builtin_amdgcn_s_setprio(1);
        grp(0, am0, ah0);
        __builtin_amdgcn_s_setprio(0);
        BARX();                                   // all waves' W reads retired
        if (t16 < 15) stageW(kt + 32);            // lands under P1/P2 MFMAs
        // ---- P1: row-groups 1-3 ----
        short8 am1 = *(const short8*)&Ms[b][(1 * 16 + l16) * 32 + fsw];
        short8 ah1 = *(const short8*)&Hs[b][(1 * 16 + l16) * 32 + fsw];
        short8 am2 = *(const short8*)&Ms[b][(2 * 16 + l16) * 32 + fsw];
        short8 ah2 = *(const short8*)&Hs[b][(2 * 16 + l16) * 32 + fsw];
        short8 am3 = *(const short8*)&Ms[b][(3 * 16 + l16) * 32 + fsw];
        short8 ah3 = *(const short8*)&Hs[b][(3 * 16 + l16) * 32 + fsw];
        BARX();
        LGKM0();
        __builtin_amdgcn_s_setprio(1);
        grp(1, am1, ah1); grp(2, am2, ah2); grp(3, am3, ah3);
        __builtin_amdgcn_s_setprio(0);
        BARX();
        // ---- P2: row-groups 4-7 ----
        short8 am4 = *(const short8*)&Ms[b][(4 * 16 + l16) * 32 + fsw];
        short8 ah4 = *(const short8*)&Hs[b][(4 * 16 + l16) * 32 + fsw];
        short8 am5 = *(const short8*)&Ms[b][(5 * 16 + l16) * 32 + fsw];
        short8 ah5 = *(const short8*)&Hs[b][(5 * 16 + l16) * 32 + fsw];
        short8 am6 = *(const short8*)&Ms[b][(6 * 16 + l16) * 32 + fsw];
        short8 ah6 = *(const short8*)&Hs[b][(6 * 16 + l16) * 32 + fsw];
        short8 am7 = *(const short8*)&Ms[b][(7 * 16 + l16) * 32 + fsw];
        short8 ah7 = *(const short8*)&Hs[b][(7 * 16 + l16) * 32 + fsw];
        BARX();
        LGKM0();
        __builtin_amdgcn_s_setprio(1);
        grp(4, am4, ah4); grp(5, am5, ah5); grp(6, am6, ah6); grp(7, am7, ah7);
        __builtin_amdgcn_s_setprio(0);
        BARX();                                   // all reads of MH[b] retired
        if (t16 < 14) stageMH(kt + 64, b);        // ~full-iter window
    }
    // ---- epilogue: gates -> stage z, (1-z)*n (f32, halves) -> coalesced RMW ----
    float* Zs32 = (float*)Ws;                     // [64][66] f32
    float* Ps32 = Zs32 + 64 * 66;                 // [64][66] f32 (33.8 KB total)
    int colL = wv * 16 + l16;
    int col = col0 + colL;
    float brz = bih[col] + bhh[col];
    float bzz = bih[HD + col] + bhh[HD + col];
    float bin_ = bih[2 * HD + col];
    float bhn_ = bhh[2 * HD + col];
    const unsigned short* hp = (const unsigned short*)Hc;
    unsigned short* op = (unsigned short*)Hn;
#pragma unroll
    for (int hhalf = 0; hhalf < 2; hhalf++) {
#pragma unroll
        for (int i = 0; i < 4; i++) {
            int ii = hhalf * 4 + i;
#pragma unroll
            for (int r = 0; r < 4; r++) {
                int rowL = i * 16 + quad * 4 + r;  // 0..63 within half
                float rg = sigmoidf_(aR[ii][r] + brz);
                float zg = sigmoidf_(aZ[ii][r] + bzz);
                float ng = tanhf(aI[ii][r] + bin_ + rg * (aHn[ii][r] + bhn_));
                Zs32[rowL * 66 + colL] = zg;
                Ps32[rowL * 66 + colL] = (1.0f - zg) * ng;
            }
        }
        __syncthreads();
#pragma unroll
        for (int sub = 0; sub < 2; sub++) {
            int rowL = sub * 32 + (tid >> 3);
            int row = row0 + hhalf * 64 + rowL;
            int cc = (tid & 7) * 8;
            if (row < n) {
                uint4 hv = *(const uint4*)&hp[(size_t)row * HD + col0 + cc];
                unsigned int hw[4] = {hv.x, hv.y, hv.z, hv.w};
                unsigned int ow[4];
#pragma unroll
                for (int q = 0; q < 4; q++) {
                    float h0 = b2f((unsigned short)(hw[q] & 0xffffu));
                    float h1 = b2f((unsigned short)(hw[q] >> 16));
                    float z0 = Zs32[rowL * 66 + cc + 2 * q];
                    float z1 = Zs32[rowL * 66 + cc + 2 * q + 1];
                    float p0 = Ps32[rowL * 66 + cc + 2 * q];
                    float p1 = Ps32[rowL * 66 + cc + 2 * q + 1];
                    float o0 = fmaf(z0, h0, p0);
                    float o1 = fmaf(z1, h1, p1);
                    ow[q] = ((unsigned int)f2b(o1) << 16) | f2b(o0);
                }
                uint4 ov = {ow[0], ow[1], ow[2], ow[3]};
                *(uint4*)&op[(size_t)row * HD + col0 + cc] = ov;
            }
        }
        __syncthreads();
    }
}

// ---------------- CSR build -------------------------------------------------------
__global__ __launch_bounds__(256) void deg_kernel(const int* __restrict__ dst,
                                                  int* __restrict__ deg) {
    int e = blockIdx.x * 256 + threadIdx.x;
    if (e < N_EDGES) atomicAdd(&deg[dst[e]], 1);
}

__global__ __launch_bounds__(1024) void scan_kernel(const int* __restrict__ deg,
                                                    int* __restrict__ offs) {
    __shared__ int buf[1024];
    __shared__ int carry_s;
    int tid = threadIdx.x;
    if (tid == 0) carry_s = 0;
    __syncthreads();
    for (int base = 0; base < N_NODES; base += 1024) {
        int v = (base + tid < N_NODES) ? deg[base + tid] : 0;
        buf[tid] = v;
        __syncthreads();
        for (int s = 1; s < 1024; s <<= 1) {
            int t = (tid >= s) ? buf[tid - s] : 0;
            __syncthreads();
            buf[tid] += t;
            __syncthreads();
        }
        int incl = buf[tid];
        if (base + tid < N_NODES) offs[base + tid] = carry_s + incl - v;
        __syncthreads();
        if (tid == 0) carry_s += buf[1023];
        __syncthreads();
    }
    if (tid == 0) offs[N_NODES] = carry_s;
}

__global__ __launch_bounds__(256) void bucket_kernel(const int* __restrict__ src,
                                                     const int* __restrict__ dst,
                                                     const int* __restrict__ offs,
                                                     int* __restrict__ cursor,
                                                     unsigned short* __restrict__ elist) {
    int e = blockIdx.x * 256 + threadIdx.x;
    if (e >= N_EDGES) return;
    int d = dst[e];
    int pos = atomicAdd(&cursor[d], 1);
    elist[offs[d] + pos] = (unsigned short)src[e];
}

// ---------------- gather-sum ------------------------------------------------------
__global__ __launch_bounds__(256) void gather_kernel(const bf16* __restrict__ msg,
                                                     bf16* __restrict__ m,
                                                     const unsigned short* __restrict__ elist,
                                                     const int* __restrict__ offs) {
    int nid = blockIdx.x, tid = threadIdx.x;
    int beg = offs[nid], end = offs[nid + 1];
    const unsigned int* mp = (const unsigned int*)msg;
    unsigned int u = mp[(size_t)nid * 256 + tid];
    float ax = b2f((unsigned short)(u & 0xffffu));
    float ay = b2f((unsigned short)(u >> 16));
    int e = beg;
    for (; e + 3 < end; e += 4) {
        unsigned int v0 = mp[(size_t)elist[e] * 256 + tid];
        unsigned int v1 = mp[(size_t)elist[e + 1] * 256 + tid];
        unsigned int v2 = mp[(size_t)elist[e + 2] * 256 + tid];
        unsigned int v3 = mp[(size_t)elist[e + 3] * 256 + tid];
        ax += b2f((unsigned short)(v0 & 0xffffu)) + b2f((unsigned short)(v1 & 0xffffu)) +
              b2f((unsigned short)(v2 & 0xffffu)) + b2f((unsigned short)(v3 & 0xffffu));
        ay += b2f((unsigned short)(v0 >> 16)) + b2f((unsigned short)(v1 >> 16)) +
              b2f((unsigned short)(v2 >> 16)) + b2f((unsigned short)(v3 >> 16));
    }
    for (; e < end; e++) {
        unsigned int v0 = mp[(size_t)elist[e] * 256 + tid];
        ax += b2f((unsigned short)(v0 & 0xffffu));
        ay += b2f((unsigned short)(v0 >> 16));
    }
    unsigned int out = ((unsigned int)f2b(ay) << 16) | (unsigned int)f2b(ax);
    ((unsigned int*)m)[(size_t)nid * 256 + tid] = out;
}

// ---------------- pooling (segmented, batch sorted -> no atomics) -----------------
__global__ __launch_bounds__(256) void pool_kernel(const bf16* __restrict__ h,
                                                   const int* __restrict__ batch,
                                                   float* __restrict__ pooled,
                                                   float* __restrict__ cnt) {
    int g = blockIdx.x;
    int col = blockIdx.y * 256 + threadIdx.x;
    // lower_bound for g and g+1 in sorted batch
    int lo = 0, hi = N_NODES;
    while (lo < hi) { int mid = (lo + hi) >> 1; if (batch[mid] < g) lo = mid + 1; else hi = mid; }
    int gs = lo;
    hi = N_NODES;
    while (lo < hi) { int mid = (lo + hi) >> 1; if (batch[mid] < g + 1) lo = mid + 1; else hi = mid; }
    int ge = lo;
    const unsigned short* hp = (const unsigned short*)h;
    float acc = 0.0f;
    int r = gs;
    for (; r + 3 < ge; r += 4) {
        acc += b2f(hp[(size_t)r * HD + col]) + b2f(hp[(size_t)(r + 1) * HD + col]) +
               b2f(hp[(size_t)(r + 2) * HD + col]) + b2f(hp[(size_t)(r + 3) * HD + col]);
    }
    for (; r < ge; r++) acc += b2f(hp[(size_t)r * HD + col]);
    pooled[g * HD + col] = acc;
    if (blockIdx.y == 0 && threadIdx.x == 0) cnt[g] = (float)(ge - gs);
}

__global__ __launch_bounds__(256) void head_kernel(const float* __restrict__ pooled,
                                                   const float* __restrict__ cnt,
                                                   const float* __restrict__ w1,
                                                   const float* __restrict__ b1,
                                                   const float* __restrict__ w2,
                                                   const float* __restrict__ b2,
                                                   float* __restrict__ out) {
    __shared__ float prow[HD];
    __shared__ float red[256];
    int g = blockIdx.x, tid = threadIdx.x;
    float c = fmaxf(cnt[g], 1.0f);
    for (int j = tid; j < HD; j += 256) prow[j] = pooled[g * HD + j] / c;
    __syncthreads();
    float acc = b1[tid];
    for (int k = 0; k < HD; k++) acc = fmaf(prow[k], w1[k * 256 + tid], acc);
    red[tid] = fmaxf(acc, 0.0f) * w2[tid];
    __syncthreads();
    for (int s = 128; s > 0; s >>= 1) {
        if (tid < s) red[tid] += red[tid + s];
        __syncthreads();
    }
    if (tid == 0) out[g] = red[0] + b2[0];
}

// ---------------- launch ----------------------------------------------------------
extern "C" void kernel_launch(void* const* d_in, const int* in_sizes, int n_in,
                              void* d_out, int out_size, void* d_ws, size_t ws_size,
                              hipStream_t stream) {
    const float* x = (const float*)d_in[0];
    const int* eidx = (const int*)d_in[1];
    const int* batch = (const int*)d_in[2];
    const float* enc_w = (const float*)d_in[3];
    const float* enc_b = (const float*)d_in[4];
    const float* mlp_w1 = (const float*)d_in[5];
    const float* mlp_b1 = (const float*)d_in[6];
    const float* mlp_w2 = (const float*)d_in[7];
    const float* mlp_b2 = (const float*)d_in[8];
    const float* gru_wih = (const float*)d_in[9];
    const float* gru_whh = (const float*)d_in[10];
    const float* gru_bih = (const float*)d_in[11];
    const float* gru_bhh = (const float*)d_in[12];
    const float* head_w1 = (const float*)d_in[13];
    const float* head_b1 = (const float*)d_in[14];
    const float* head_w2 = (const float*)d_in[15];
    const float* head_b2 = (const float*)d_in[16];
    const int* src = eidx;
    const int* dst = eidx + N_EDGES;

    const size_t NH = (size_t)N_NODES * HD;
    char* p = (char*)d_ws;
    auto alloc = [&](size_t bytes) { char* q = p; p += (bytes + 255) & ~(size_t)255; return q; };
    bf16* S0 = (bf16*)alloc(NH * 2);
    bf16* S1 = (bf16*)alloc(NH * 2);
    bf16* S2 = (bf16*)alloc(NH * 2);
    bf16* w1tH = (bf16*)alloc((size_t)NL * HD * HD * 2);
    bf16* w1tL = (bf16*)alloc((size_t)NL * HD * HD * 2);
    bf16* w2tH = (bf16*)alloc((size_t)NL * HD * HD * 2);
    bf16* w2tL = (bf16*)alloc((size_t)NL * HD * HD * 2);
    bf16* wihtH = (bf16*)alloc((size_t)NL * 3 * HD * HD * 2);
    bf16* wihtL = (bf16*)alloc((size_t)NL * 3 * HD * HD * 2);
    bf16* whhtH = (bf16*)alloc((size_t)NL * 3 * HD * HD * 2);
    bf16* whhtL = (bf16*)alloc((size_t)NL * 3 * HD * HD * 2);
    float* pooled = (float*)alloc((size_t)N_GRAPH * HD * 4);
    float* cnt = (float*)alloc(N_GRAPH * 4);
    int* deg = (int*)alloc((N_NODES + 1) * 4);  // also cursor
    int* offs = (int*)alloc((N_NODES + 1) * 4);
    unsigned short* elist = (unsigned short*)alloc((size_t)N_EDGES * 2);
    // total ~144 MB (proven-safe envelope)

    twcvt_kernel<<<dim3(16, 16, NL), 256, 0, stream>>>(mlp_w1, w1tH, w1tL, HD);
    twcvt_kernel<<<dim3(16, 16, NL), 256, 0, stream>>>(mlp_w2, w2tH, w2tL, HD);
    twcvt_kernel<<<dim3(48, 16, NL), 256, 0, stream>>>(gru_wih, wihtH, wihtL, 3 * HD);
    twcvt_kernel<<<dim3(48, 16, NL), 256, 0, stream>>>(gru_whh, whhtH, whhtL, 3 * HD);

    hipMemsetAsync(deg, 0, (N_NODES + 1) * sizeof(int), stream);
    deg_kernel<<<(N_EDGES + 255) / 256, 256, 0, stream>>>(dst, deg);
    scan_kernel<<<1, 1024, 0, stream>>>(deg, offs);
    hipMemsetAsync(deg, 0, (N_NODES + 1) * sizeof(int), stream);
    bucket_kernel<<<(N_EDGES + 255) / 256, 256, 0, stream>>>(src, dst, offs, deg, elist);

    enc_kernel<<<N_NODES, 256, 0, stream>>>(x, enc_w, enc_b, S0);

    bf16* hcur = S0;
    bf16* hoth = S1;
    // XCD-banded 1-D grids (proven FETCH win in R5)
    int ggrid = 8 * ((NRG + 7) / 8) * 4;    // 960
    int ugrid = 8 * ((NRG + 3) / 4) * 4;    // 1888

    for (int l = 0; l < NL; l++) {
        size_t wsq = (size_t)l * HD * HD;
        size_t wgq = (size_t)l * 3 * HD * HD;
        const float* b1 = mlp_b1 + (size_t)l * HD;
        const float* b2 = mlp_b2 + (size_t)l * HD;
        const float* bih = gru_bih + (size_t)l * 3 * HD;
        const float* bhh = gru_bhh + (size_t)l * 3 * HD;

        gemm_mfma<true><<<ggrid, 256, 0, stream>>>(hcur, w1tH + wsq, w1tL + wsq, b1, hoth, N_NODES);
        gemm_mfma<false><<<ggrid, 256, 0, stream>>>(hoth, w2tH + wsq, w2tL + wsq, b2, S2, N_NODES);
        gather_kernel<<<N_NODES, 256, 0, stream>>>(S2, hoth, elist, offs);
        gru_mfma<<<ugrid, 256, 0, stream>>>(hoth, hcur, wihtH + wgq, wihtL + wgq,
                                            whhtH + wgq, whhtL + wgq, bih, bhh, S2, N_NODES);
        bf16* newh = S2;
        S2 = hcur;
        hcur = newh;
    }

    pool_kernel<<<dim3(N_GRAPH, 2), 256, 0, stream>>>(hcur, batch, pooled, cnt);
    head_kernel<<<N_GRAPH, 256, 0, stream>>>(pooled, cnt, head_w1, head_b1, head_w2, head_b2,
                                             (float*)d_out);
}